// Round 1
// baseline (2240.961 us; speedup 1.0000x reference)
//
#include <hip/hip_runtime.h>

#define D 128
#define EPS 1e-5f

// ---------------------------------------------------------------------------
// Degree histogram: integer atomics (always HW) into deg buffer (as int).
__global__ __launch_bounds__(256) void k_deg(const int* __restrict__ dst,
                                             int* __restrict__ deg, int E) {
  int i = blockIdx.x * 256 + threadIdx.x;
  if (i < E) atomicAdd(&deg[dst[i]], 1);
}

// In place: reinterpret int count -> dinv = rsqrt(count + 1)  (+1 self loop)
__global__ __launch_bounds__(256) void k_dinv(float* __restrict__ buf, int n) {
  int i = blockIdx.x * 256 + threadIdx.x;
  if (i < n) {
    int c = ((const int*)buf)[i];
    buf[i] = rsqrtf((float)c + 1.0f);
  }
}

// ---------------------------------------------------------------------------
// GEMM: out[r, :] = in[r, :] @ W   (128x128 W), 64 rows per block.
// k-chunked (2 chunks of 64) so LDS = 32KB(W) + 16KB(xT) = 48KB.
// Safe when out == in (all global reads happen before first barrier-protected
// compute; each block writes only its own rows).
__global__ __launch_bounds__(256) void k_gemm(const float* in, const float* W,
                                              float* out, int nrows) {
  __shared__ float sW[64 * 128];   // sW[k][c], k within chunk
  __shared__ float sX[64 * 64];    // xT[k][r], k within chunk
  const int tid  = threadIdx.x;
  const int row0 = blockIdx.x * 64;
  const int cg = tid & 31;         // col group: 4 cols
  const int rg = tid >> 5;         // row group: 8 rows
  const int j0 = cg * 4;
  const int r0 = rg * 8;

  float acc[8][4];
#pragma unroll
  for (int i = 0; i < 8; i++)
#pragma unroll
    for (int j = 0; j < 4; j++) acc[i][j] = 0.0f;

  for (int k0 = 0; k0 < 128; k0 += 64) {
    // stage W chunk: 8192 floats = 2048 float4, 8 per thread
#pragma unroll
    for (int t = 0; t < 8; t++) {
      int f = tid + 256 * t;            // float4 index into sW
      int kk = f >> 5;                  // 0..63
      int c4 = f & 31;                  // 0..31
      float4 w = ((const float4*)W)[(k0 + kk) * 32 + c4];
      ((float4*)sW)[f] = w;
    }
    // stage x chunk transposed: 64 rows x 16 float4 = 1024 float4, 4/thread
#pragma unroll
    for (int t = 0; t < 4; t++) {
      int f = tid + 256 * t;
      int c4 = f & 15;                  // float4 within the 64-wide k chunk
      int r  = f >> 4;                  // 0..63
      float4 v = make_float4(0.f, 0.f, 0.f, 0.f);
      if (row0 + r < nrows)
        v = *(const float4*)(in + (size_t)(row0 + r) * D + k0 + c4 * 4);
      sX[(c4 * 4 + 0) * 64 + r] = v.x;
      sX[(c4 * 4 + 1) * 64 + r] = v.y;
      sX[(c4 * 4 + 2) * 64 + r] = v.z;
      sX[(c4 * 4 + 3) * 64 + r] = v.w;
    }
    __syncthreads();
#pragma unroll 4
    for (int k = 0; k < 64; k++) {
      float4 w  = *(const float4*)(sW + k * 128 + j0);
      float4 a0 = *(const float4*)(sX + k * 64 + r0);
      float4 a1 = *(const float4*)(sX + k * 64 + r0 + 4);
      float a[8] = {a0.x, a0.y, a0.z, a0.w, a1.x, a1.y, a1.z, a1.w};
#pragma unroll
      for (int i = 0; i < 8; i++) {
        acc[i][0] = fmaf(a[i], w.x, acc[i][0]);
        acc[i][1] = fmaf(a[i], w.y, acc[i][1]);
        acc[i][2] = fmaf(a[i], w.z, acc[i][2]);
        acc[i][3] = fmaf(a[i], w.w, acc[i][3]);
      }
    }
    __syncthreads();
  }
#pragma unroll
  for (int i = 0; i < 8; i++) {
    int rr = row0 + r0 + i;
    if (rr < nrows)
      *(float4*)(out + (size_t)rr * D + j0) =
          make_float4(acc[i][0], acc[i][1], acc[i][2], acc[i][3]);
  }
}

// ---------------------------------------------------------------------------
// Edge scatter: agg[dst] += h[src] * dinv[src] * dinv[dst]
// 32 lanes per edge, float4 per lane, HW f32 atomics.
__global__ __launch_bounds__(256) void k_scatter(const float* __restrict__ h,
                                                 const int* __restrict__ src,
                                                 const int* __restrict__ dst,
                                                 const float* __restrict__ dinv,
                                                 float* __restrict__ agg, int E) {
  int e = blockIdx.x * 8 + (threadIdx.x >> 5);
  if (e >= E) return;
  int c = (threadIdx.x & 31) * 4;
  int s = src[e], d = dst[e];
  float nrm = dinv[s] * dinv[d];
  float4 v = *(const float4*)(h + (size_t)s * D + c);
  float* p = agg + (size_t)d * D + c;
  unsafeAtomicAdd(p + 0, v.x * nrm);
  unsafeAtomicAdd(p + 1, v.y * nrm);
  unsafeAtomicAdd(p + 2, v.z * nrm);
  unsafeAtomicAdd(p + 3, v.w * nrm);
}

// ---------------------------------------------------------------------------
// Fused epilogue: v = agg + h*dinv^2 + b; LN(v)*g + bln; relu; (+resid); store
// One wave (64 lanes) per row, 2 floats per lane. out may alias agg or h
// (row-elementwise).
__global__ __launch_bounds__(256) void k_ln(const float* agg, const float* h,
                                            const float* __restrict__ dinv,
                                            const float* __restrict__ b,
                                            const float* __restrict__ g,
                                            const float* __restrict__ bln,
                                            const float* __restrict__ resid,
                                            float* out, int n) {
  int row  = blockIdx.x * 4 + (threadIdx.x >> 6);
  int lane = threadIdx.x & 63;
  if (row >= n) return;
  float sn = dinv[row];
  sn = sn * sn;
  int d0 = lane * 2;
  size_t base = (size_t)row * D + d0;
  float2 a  = *(const float2*)(agg + base);
  float2 hh = *(const float2*)(h + base);
  float2 bb = *(const float2*)(b + d0);
  float vx = a.x + hh.x * sn + bb.x;
  float vy = a.y + hh.y * sn + bb.y;

  float sum = vx + vy;
#pragma unroll
  for (int o = 32; o >= 1; o >>= 1) sum += __shfl_xor(sum, o, 64);
  float mu = sum * (1.0f / 128.0f);
  float dx = vx - mu, dy = vy - mu;
  float vs = dx * dx + dy * dy;
#pragma unroll
  for (int o = 32; o >= 1; o >>= 1) vs += __shfl_xor(vs, o, 64);
  float inv = rsqrtf(vs * (1.0f / 128.0f) + EPS);

  float2 gg = *(const float2*)(g + d0);
  float2 bl = *(const float2*)(bln + d0);
  float ox = fmaxf(dx * inv * gg.x + bl.x, 0.0f);
  float oy = fmaxf(dy * inv * gg.y + bl.y, 0.0f);
  if (resid) {
    float2 rr = *(const float2*)(resid + base);
    ox += rr.x;
    oy += rr.y;
  }
  *(float2*)(out + base) = make_float2(ox, oy);
}

// ---------------------------------------------------------------------------
extern "C" void kernel_launch(void* const* d_in, const int* in_sizes, int n_in,
                              void* d_out, int out_size, void* d_ws, size_t ws_size,
                              hipStream_t stream) {
  const float* x    = (const float*)d_in[0];
  const int*   ei   = (const int*)d_in[1];
  const float* W1   = (const float*)d_in[2];
  const float* b1   = (const float*)d_in[3];
  const float* g1   = (const float*)d_in[4];
  const float* bl1  = (const float*)d_in[5];
  const float* W2   = (const float*)d_in[6];
  const float* b2   = (const float*)d_in[7];
  const float* g2   = (const float*)d_in[8];
  const float* bl2  = (const float*)d_in[9];

  const int N = in_sizes[0] / D;
  const int E = in_sizes[1] / 2;
  const int* src = ei;
  const int* dst = ei + E;

  // ws layout: [dinv: N floats][A: N*D floats]
  float* dinv = (float*)d_ws;
  float* A    = (float*)((char*)d_ws + (((size_t)N * 4 + 255) & ~(size_t)255));
  float* O    = (float*)d_out;

  const size_t nd_bytes = (size_t)N * D * sizeof(float);

  // degrees -> dinv
  hipMemsetAsync(dinv, 0, (size_t)N * 4, stream);
  k_deg<<<(E + 255) / 256, 256, 0, stream>>>(dst, (int*)dinv, E);
  k_dinv<<<(N + 255) / 256, 256, 0, stream>>>(dinv, N);

  // ---- layer 1 ----
  k_gemm<<<(N + 63) / 64, 256, 0, stream>>>(x, W1, A, N);        // h1 -> A
  hipMemsetAsync(O, 0, nd_bytes, stream);
  k_scatter<<<(E + 7) / 8, 256, 0, stream>>>(A, src, dst, dinv, O, E);
  // y1 = relu(LN(agg + h1/deg + b1)) -> A (in place over h1)
  k_ln<<<(N + 3) / 4, 256, 0, stream>>>(O, A, dinv, b1, g1, bl1, nullptr, A, N);

  // ---- layer 2 ----
  k_gemm<<<(N + 63) / 64, 256, 0, stream>>>(A, W2, A, N);        // h2 -> A (in place)
  hipMemsetAsync(O, 0, nd_bytes, stream);
  k_scatter<<<(E + 7) / 8, 256, 0, stream>>>(A, src, dst, dinv, O, E);
  // out = relu(LN(agg + h2/deg + b2)) + x -> O (in place over agg)
  k_ln<<<(N + 3) / 4, 256, 0, stream>>>(O, A, dinv, b2, g2, bl2, x, O, N);
}

// Round 2
// 337.787 us; speedup vs baseline: 6.6342x; 6.6342x over previous
//
#include <hip/hip_runtime.h>

#define D 128
#define EPS 1e-5f

// ---------------------------------------------------------------------------
// Degree histogram (int atomics are cheap — R1 evidence: k_deg not in top-5).
__global__ __launch_bounds__(256) void k_deg(const int* __restrict__ dst,
                                             int* __restrict__ deg, int E) {
  int i = blockIdx.x * 256 + threadIdx.x;
  if (i < E) atomicAdd(&deg[dst[i]], 1);
}

__global__ __launch_bounds__(256) void k_dinv(const int* __restrict__ deg,
                                              float* __restrict__ dinv, int n) {
  int i = blockIdx.x * 256 + threadIdx.x;
  if (i < n) dinv[i] = rsqrtf((float)deg[i] + 1.0f);
}

// CSR range allocation: wave-level inclusive scan of deg, one atomic per wave.
__global__ __launch_bounds__(256) void k_alloc(const int* __restrict__ deg,
                                               int* __restrict__ start,
                                               int* __restrict__ cursor,
                                               int* __restrict__ counter, int n) {
  int i = blockIdx.x * 256 + threadIdx.x;
  int lane = threadIdx.x & 63;
  int d = (i < n) ? deg[i] : 0;
  int v = d;
#pragma unroll
  for (int o = 1; o < 64; o <<= 1) {
    int t = __shfl_up(v, o, 64);
    if (lane >= o) v += t;
  }
  int total = __shfl(v, 63, 64);
  int base = 0;
  if (lane == 0) base = atomicAdd(counter, total);
  base = __shfl(base, 0, 64);
  if (i < n) {
    int st = base + v - d;   // exclusive prefix within wave
    start[i] = st;
    cursor[i] = st;
  }
}

// Counting-sort fill: csr_src[pos] = src, csr_w[pos] = dinv[s]*dinv[d].
__global__ __launch_bounds__(256) void k_fill(const int* __restrict__ src,
                                              const int* __restrict__ dst,
                                              const float* __restrict__ dinv,
                                              int* __restrict__ cursor,
                                              int* __restrict__ csr_src,
                                              float* __restrict__ csr_w, int E) {
  int e = blockIdx.x * 256 + threadIdx.x;
  if (e >= E) return;
  int s = src[e], d = dst[e];
  int pos = atomicAdd(&cursor[d], 1);
  csr_src[pos] = s;
  csr_w[pos] = dinv[s] * dinv[d];
}

// ---------------------------------------------------------------------------
// GEMM: out[r, :] = in[r, :] @ W   (128x128 W), 64 rows per block.
__global__ __launch_bounds__(256) void k_gemm(const float* in, const float* W,
                                              float* out, int nrows) {
  __shared__ float sW[64 * 128];   // sW[k][c], k within chunk
  __shared__ float sX[64 * 64];    // xT[k][r], k within chunk
  const int tid  = threadIdx.x;
  const int row0 = blockIdx.x * 64;
  const int cg = tid & 31;
  const int rg = tid >> 5;
  const int j0 = cg * 4;
  const int r0 = rg * 8;

  float acc[8][4];
#pragma unroll
  for (int i = 0; i < 8; i++)
#pragma unroll
    for (int j = 0; j < 4; j++) acc[i][j] = 0.0f;

  for (int k0 = 0; k0 < 128; k0 += 64) {
#pragma unroll
    for (int t = 0; t < 8; t++) {
      int f = tid + 256 * t;
      int kk = f >> 5;
      int c4 = f & 31;
      float4 w = ((const float4*)W)[(k0 + kk) * 32 + c4];
      ((float4*)sW)[f] = w;
    }
#pragma unroll
    for (int t = 0; t < 4; t++) {
      int f = tid + 256 * t;
      int c4 = f & 15;
      int r  = f >> 4;
      float4 v = make_float4(0.f, 0.f, 0.f, 0.f);
      if (row0 + r < nrows)
        v = *(const float4*)(in + (size_t)(row0 + r) * D + k0 + c4 * 4);
      sX[(c4 * 4 + 0) * 64 + r] = v.x;
      sX[(c4 * 4 + 1) * 64 + r] = v.y;
      sX[(c4 * 4 + 2) * 64 + r] = v.z;
      sX[(c4 * 4 + 3) * 64 + r] = v.w;
    }
    __syncthreads();
#pragma unroll 4
    for (int k = 0; k < 64; k++) {
      float4 w  = *(const float4*)(sW + k * 128 + j0);
      float4 a0 = *(const float4*)(sX + k * 64 + r0);
      float4 a1 = *(const float4*)(sX + k * 64 + r0 + 4);
      float a[8] = {a0.x, a0.y, a0.z, a0.w, a1.x, a1.y, a1.z, a1.w};
#pragma unroll
      for (int i = 0; i < 8; i++) {
        acc[i][0] = fmaf(a[i], w.x, acc[i][0]);
        acc[i][1] = fmaf(a[i], w.y, acc[i][1]);
        acc[i][2] = fmaf(a[i], w.z, acc[i][2]);
        acc[i][3] = fmaf(a[i], w.w, acc[i][3]);
      }
    }
    __syncthreads();
  }
#pragma unroll
  for (int i = 0; i < 8; i++) {
    int rr = row0 + r0 + i;
    if (rr < nrows)
      *(float4*)(out + (size_t)rr * D + j0) =
          make_float4(acc[i][0], acc[i][1], acc[i][2], acc[i][3]);
  }
}

// ---------------------------------------------------------------------------
// Fused CSR gather + self-loop + bias + LayerNorm + ReLU (+residual).
// One wave per dst row, float2 per lane. No atomics.
__global__ __launch_bounds__(256) void k_gather_ln(
    const float* __restrict__ h, const int* __restrict__ start,
    const int* __restrict__ deg, const float* __restrict__ dinv,
    const int* __restrict__ csr_src, const float* __restrict__ csr_w,
    const float* __restrict__ b, const float* __restrict__ g,
    const float* __restrict__ bln, const float* __restrict__ resid,
    float* __restrict__ out, int n) {
  int row  = blockIdx.x * 4 + (threadIdx.x >> 6);
  int lane = threadIdx.x & 63;
  if (row >= n) return;
  int beg = start[row];
  int cnt = deg[row];
  float sn = dinv[row];
  sn *= sn;
  int d0 = lane * 2;
  size_t base = (size_t)row * D + d0;

  // acc = h[row]*dinv^2 + b   (self-loop + bias)
  float2 hh = *(const float2*)(h + base);
  float2 bb = *(const float2*)(b + d0);
  float ax = fmaf(hh.x, sn, bb.x);
  float ay = fmaf(hh.y, sn, bb.y);

  for (int j0 = 0; j0 < cnt; j0 += 64) {
    int m = min(cnt - j0, 64);
    int   se = 0;
    float we = 0.0f;
    if (lane < m) {
      se = csr_src[beg + j0 + lane];
      we = csr_w[beg + j0 + lane];
    }
    int j = 0;
    for (; j + 1 < m; j += 2) {           // unroll-2: two gathers in flight
      int   s0 = __shfl(se, j, 64),     s1 = __shfl(se, j + 1, 64);
      float w0 = __shfl(we, j, 64),     w1 = __shfl(we, j + 1, 64);
      float2 v0 = *(const float2*)(h + (size_t)s0 * D + d0);
      float2 v1 = *(const float2*)(h + (size_t)s1 * D + d0);
      ax = fmaf(v0.x, w0, ax);
      ay = fmaf(v0.y, w0, ay);
      ax = fmaf(v1.x, w1, ax);
      ay = fmaf(v1.y, w1, ay);
    }
    if (j < m) {
      int   s0 = __shfl(se, j, 64);
      float w0 = __shfl(we, j, 64);
      float2 v0 = *(const float2*)(h + (size_t)s0 * D + d0);
      ax = fmaf(v0.x, w0, ax);
      ay = fmaf(v0.y, w0, ay);
    }
  }

  // LayerNorm over 128 elems spread 2-per-lane across the wave.
  float sum = ax + ay;
#pragma unroll
  for (int o = 32; o >= 1; o >>= 1) sum += __shfl_xor(sum, o, 64);
  float mu = sum * (1.0f / 128.0f);
  float dx = ax - mu, dy = ay - mu;
  float vs = dx * dx + dy * dy;
#pragma unroll
  for (int o = 32; o >= 1; o >>= 1) vs += __shfl_xor(vs, o, 64);
  float inv = rsqrtf(vs * (1.0f / 128.0f) + EPS);

  float2 gg = *(const float2*)(g + d0);
  float2 bl = *(const float2*)(bln + d0);
  float ox = fmaxf(dx * inv * gg.x + bl.x, 0.0f);
  float oy = fmaxf(dy * inv * gg.y + bl.y, 0.0f);
  if (resid) {
    float2 rr = *(const float2*)(resid + base);
    ox += rr.x;
    oy += rr.y;
  }
  *(float2*)(out + base) = make_float2(ox, oy);
}

// ---------------------------------------------------------------------------
extern "C" void kernel_launch(void* const* d_in, const int* in_sizes, int n_in,
                              void* d_out, int out_size, void* d_ws, size_t ws_size,
                              hipStream_t stream) {
  const float* x    = (const float*)d_in[0];
  const int*   ei   = (const int*)d_in[1];
  const float* W1   = (const float*)d_in[2];
  const float* b1   = (const float*)d_in[3];
  const float* g1   = (const float*)d_in[4];
  const float* bl1  = (const float*)d_in[5];
  const float* W2   = (const float*)d_in[6];
  const float* b2   = (const float*)d_in[7];
  const float* g2   = (const float*)d_in[8];
  const float* bl2  = (const float*)d_in[9];

  const int N = in_sizes[0] / D;
  const int E = in_sizes[1] / 2;
  const int* src = ei;
  const int* dst = ei + E;

  // ws layout
  size_t off = 0;
  auto walloc = [&](size_t bytes) {
    void* p = (char*)d_ws + off;
    off = (off + bytes + 255) & ~(size_t)255;
    return p;
  };
  int*   deg     = (int*)walloc((size_t)N * 4);
  float* dinv    = (float*)walloc((size_t)N * 4);
  int*   startp  = (int*)walloc((size_t)N * 4);
  int*   cursor  = (int*)walloc((size_t)N * 4);
  int*   counter = (int*)walloc(256);
  int*   csr_src = (int*)walloc((size_t)E * 4);
  float* csr_w   = (float*)walloc((size_t)E * 4);
  float* A       = (float*)walloc((size_t)N * D * 4);
  float* O       = (float*)d_out;

  // ---- CSR build (shared across both layers) ----
  hipMemsetAsync(deg, 0, (size_t)N * 4, stream);
  hipMemsetAsync(counter, 0, 4, stream);
  k_deg<<<(E + 255) / 256, 256, 0, stream>>>(dst, deg, E);
  k_dinv<<<(N + 255) / 256, 256, 0, stream>>>(deg, dinv, N);
  k_alloc<<<(N + 255) / 256, 256, 0, stream>>>(deg, startp, cursor, counter, N);
  k_fill<<<(E + 255) / 256, 256, 0, stream>>>(src, dst, dinv, cursor, csr_src, csr_w, E);

  // ---- layer 1 ----
  k_gemm<<<(N + 63) / 64, 256, 0, stream>>>(x, W1, A, N);   // h1 -> A
  k_gather_ln<<<(N + 3) / 4, 256, 0, stream>>>(A, startp, deg, dinv, csr_src,
                                               csr_w, b1, g1, bl1, nullptr, O, N);
  // ---- layer 2 ----
  k_gemm<<<(N + 63) / 64, 256, 0, stream>>>(O, W2, A, N);   // h2 -> A
  k_gather_ln<<<(N + 3) / 4, 256, 0, stream>>>(A, startp, deg, dinv, csr_src,
                                               csr_w, b2, g2, bl2, x, O, N);
}

// Round 3
// 268.960 us; speedup vs baseline: 8.3320x; 1.2559x over previous
//
#include <hip/hip_runtime.h>

#define D 128
#define EPS 1e-5f

typedef unsigned int u32;
typedef unsigned short u16;
typedef __attribute__((ext_vector_type(8))) short short8;   // 8 bf16 (4 VGPRs)
typedef __attribute__((ext_vector_type(4))) float f32x4;
typedef __attribute__((ext_vector_type(8))) u16 u16x8;
typedef __attribute__((ext_vector_type(4))) u16 u16x4;

__device__ inline u16 f2b(float f) {            // fp32 -> bf16, RNE
  u32 u = __builtin_bit_cast(u32, f);
  return (u16)((u + 0x7fffu + ((u >> 16) & 1u)) >> 16);
}
__device__ inline float bf_lo(u32 u) { return __builtin_bit_cast(float, u << 16); }
__device__ inline float bf_hi(u32 u) { return __builtin_bit_cast(float, u & 0xffff0000u); }

// ---------------------------------------------------------------------------
// CSR build
__global__ __launch_bounds__(256) void k_deg(const int* __restrict__ dst,
                                             int* __restrict__ deg, int E) {
  int i = blockIdx.x * 256 + threadIdx.x;
  if (i < E) atomicAdd(&deg[dst[i]], 1);
}

__global__ __launch_bounds__(256) void k_dinv(const int* __restrict__ deg,
                                              float* __restrict__ dinv, int n) {
  int i = blockIdx.x * 256 + threadIdx.x;
  if (i < n) dinv[i] = rsqrtf((float)deg[i] + 1.0f);
}

__global__ __launch_bounds__(256) void k_alloc(const int* __restrict__ deg,
                                               int* __restrict__ start,
                                               int* __restrict__ cursor,
                                               int* __restrict__ counter, int n) {
  int i = blockIdx.x * 256 + threadIdx.x;
  int lane = threadIdx.x & 63;
  int d = (i < n) ? deg[i] : 0;
  int v = d;
#pragma unroll
  for (int o = 1; o < 64; o <<= 1) {
    int t = __shfl_up(v, o, 64);
    if (lane >= o) v += t;
  }
  int total = __shfl(v, 63, 64);
  int base = 0;
  if (lane == 0) base = atomicAdd(counter, total);
  base = __shfl(base, 0, 64);
  if (i < n) {
    int st = base + v - d;
    start[i] = st;
    cursor[i] = st;
  }
}

__global__ __launch_bounds__(256) void k_fill(const int* __restrict__ src,
                                              const int* __restrict__ dst,
                                              const float* __restrict__ dinv,
                                              int* __restrict__ cursor,
                                              int2* __restrict__ csr, int E) {
  int e = blockIdx.x * 256 + threadIdx.x;
  if (e >= E) return;
  int s = src[e], d = dst[e];
  int pos = atomicAdd(&cursor[d], 1);
  float w = dinv[s] * dinv[d];
  csr[pos] = make_int2(s, __builtin_bit_cast(int, w));
}

// W[k][c] fp32 -> Wt[c][k] bf16 (so B-fragments are contiguous in k)
__global__ __launch_bounds__(256) void k_prep(const float* __restrict__ W,
                                              u16* __restrict__ Wt) {
  int i = blockIdx.x * 256 + threadIdx.x;
  if (i < D * D) {
    int k = i >> 7, c = i & 127;
    Wt[c * D + k] = f2b(W[i]);
  }
}

// ---------------------------------------------------------------------------
// MFMA GEMM: hb[r,:] = bf16( in[r,:] @ W )  via v_mfma_f32_16x16x32_bf16.
// 64 rows/block, 4 waves; wave w covers rows w*16..w*16+15, all 128 cols.
// A-frag: A[m=lane&15][k=quad*8+j]; B-frag: B[k=quad*8+j][n=lane&15] read from
// Wt[n][k] (contiguous 16B); D: col=lane&15, row=quad*4+reg.
template <bool BF16IN>
__global__ __launch_bounds__(256) void k_gemm_mfma(const void* __restrict__ in_,
                                                   const u16* __restrict__ Wt,
                                                   u16* __restrict__ hb, int nrows) {
  __shared__ alignas(16) u16 sX[64 * 136];    // [r][k], pad 136 (2-way max)
  __shared__ alignas(16) u16 sW[128 * 136];   // [c][k]
  const int tid = threadIdx.x;
  const int row0 = blockIdx.x * 64;

  // stage Wt: 2048 16B chunks, 8/thread
#pragma unroll
  for (int t = 0; t < 8; t++) {
    int f = tid + 256 * t;
    int r = f >> 4, c8 = f & 15;
    u16x8 w = *(const u16x8*)(Wt + r * D + c8 * 8);
    *(u16x8*)(sW + r * 136 + c8 * 8) = w;
  }
  if (BF16IN) {
    const u16* in = (const u16*)in_;
#pragma unroll
    for (int t = 0; t < 4; t++) {
      int f = tid + 256 * t;
      int r = f >> 4, c8 = f & 15;
      u16x8 v = {};
      if (row0 + r < nrows) v = *(const u16x8*)(in + (size_t)(row0 + r) * D + c8 * 8);
      *(u16x8*)(sX + r * 136 + c8 * 8) = v;
    }
  } else {
    const float* in = (const float*)in_;
#pragma unroll
    for (int t = 0; t < 8; t++) {
      int f = tid + 256 * t;
      int r = f >> 5, c4 = f & 31;
      float4 v = make_float4(0.f, 0.f, 0.f, 0.f);
      if (row0 + r < nrows) v = *(const float4*)(in + (size_t)(row0 + r) * D + c4 * 4);
      u16x4 p = {f2b(v.x), f2b(v.y), f2b(v.z), f2b(v.w)};
      *(u16x4*)(sX + r * 136 + c4 * 4) = p;
    }
  }
  __syncthreads();

  const int lane = tid & 63, wv = tid >> 6;
  const int m = lane & 15, q = lane >> 4;
  const int r0 = wv * 16;

  f32x4 acc[8];
#pragma unroll
  for (int ct = 0; ct < 8; ct++) acc[ct] = (f32x4)(0.0f);

  const u16* ap = sX + (r0 + m) * 136 + q * 8;
  const u16* bp = sW + m * 136 + q * 8;
#pragma unroll
  for (int kk = 0; kk < 4; kk++) {
    short8 a = *(const short8*)(ap + kk * 32);
#pragma unroll
    for (int ct = 0; ct < 8; ct++) {
      short8 b = *(const short8*)(bp + ct * 16 * 136 + kk * 32);
      acc[ct] = __builtin_amdgcn_mfma_f32_16x16x32_bf16(a, b, acc[ct], 0, 0, 0);
    }
  }

  // epilogue: scattered bf16 stores (4 rows x 16 cols per store instr)
#pragma unroll
  for (int ct = 0; ct < 8; ct++) {
#pragma unroll
    for (int rg = 0; rg < 4; rg++) {
      int rr = row0 + r0 + q * 4 + rg;
      if (rr < nrows) hb[(size_t)rr * D + ct * 16 + m] = f2b(acc[ct][rg]);
    }
  }
}

// ---------------------------------------------------------------------------
// Fused CSR gather (bf16 h) + self-loop + bias + LayerNorm + ReLU (+residual).
// One wave per dst row; lane holds cols 2*lane, 2*lane+1 (one u32 = 2 bf16).
__global__ __launch_bounds__(256) void k_gather_ln(
    const u32* __restrict__ hb, const int* __restrict__ start,
    const int* __restrict__ deg, const float* __restrict__ dinv,
    const int2* __restrict__ csr,
    const float* __restrict__ b, const float* __restrict__ g,
    const float* __restrict__ bln, const float* __restrict__ resid,
    float* __restrict__ outf, u32* __restrict__ outb, int n) {
  int row  = blockIdx.x * 4 + (threadIdx.x >> 6);
  int lane = threadIdx.x & 63;
  if (row >= n) return;
  int beg = start[row];
  int cnt = deg[row];
  float sn = dinv[row];
  sn *= sn;
  int d0 = lane * 2;

  u32 su = hb[row * 64 + lane];
  float2 bb = *(const float2*)(b + d0);
  float ax = fmaf(bf_lo(su), sn, bb.x);
  float ay = fmaf(bf_hi(su), sn, bb.y);

  for (int j0 = 0; j0 < cnt; j0 += 64) {
    int mm = min(cnt - j0, 64);
    int2 pr = make_int2(0, 0);
    if (lane < mm) pr = csr[beg + j0 + lane];
    int j = 0;
    for (; j + 1 < mm; j += 2) {
      int   s0 = __shfl(pr.x, j, 64), s1 = __shfl(pr.x, j + 1, 64);
      float w0 = __builtin_bit_cast(float, __shfl(pr.y, j, 64));
      float w1 = __builtin_bit_cast(float, __shfl(pr.y, j + 1, 64));
      u32 u0 = hb[(size_t)s0 * 64 + lane];
      u32 u1 = hb[(size_t)s1 * 64 + lane];
      ax = fmaf(bf_lo(u0), w0, ax);
      ay = fmaf(bf_hi(u0), w0, ay);
      ax = fmaf(bf_lo(u1), w1, ax);
      ay = fmaf(bf_hi(u1), w1, ay);
    }
    if (j < mm) {
      int   s0 = __shfl(pr.x, j, 64);
      float w0 = __builtin_bit_cast(float, __shfl(pr.y, j, 64));
      u32 u0 = hb[(size_t)s0 * 64 + lane];
      ax = fmaf(bf_lo(u0), w0, ax);
      ay = fmaf(bf_hi(u0), w0, ay);
    }
  }

  float sum = ax + ay;
#pragma unroll
  for (int o = 32; o >= 1; o >>= 1) sum += __shfl_xor(sum, o, 64);
  float mu = sum * (1.0f / 128.0f);
  float dx = ax - mu, dy = ay - mu;
  float vs = dx * dx + dy * dy;
#pragma unroll
  for (int o = 32; o >= 1; o >>= 1) vs += __shfl_xor(vs, o, 64);
  float inv = rsqrtf(vs * (1.0f / 128.0f) + EPS);

  float2 gg = *(const float2*)(g + d0);
  float2 bl = *(const float2*)(bln + d0);
  float ox = fmaxf(dx * inv * gg.x + bl.x, 0.0f);
  float oy = fmaxf(dy * inv * gg.y + bl.y, 0.0f);

  if (outb) {
    outb[row * 64 + lane] = ((u32)f2b(oy) << 16) | (u32)f2b(ox);
  } else {
    size_t base = (size_t)row * D + d0;
    float2 rr = *(const float2*)(resid + base);
    *(float2*)(outf + base) = make_float2(ox + rr.x, oy + rr.y);
  }
}

// ---------------------------------------------------------------------------
extern "C" void kernel_launch(void* const* d_in, const int* in_sizes, int n_in,
                              void* d_out, int out_size, void* d_ws, size_t ws_size,
                              hipStream_t stream) {
  const float* x    = (const float*)d_in[0];
  const int*   ei   = (const int*)d_in[1];
  const float* W1   = (const float*)d_in[2];
  const float* b1   = (const float*)d_in[3];
  const float* g1   = (const float*)d_in[4];
  const float* bl1  = (const float*)d_in[5];
  const float* W2   = (const float*)d_in[6];
  const float* b2   = (const float*)d_in[7];
  const float* g2   = (const float*)d_in[8];
  const float* bl2  = (const float*)d_in[9];

  const int N = in_sizes[0] / D;
  const int E = in_sizes[1] / 2;
  const int* src = ei;
  const int* dst = ei + E;

  size_t off = 0;
  auto walloc = [&](size_t bytes) {
    void* p = (char*)d_ws + off;
    off = (off + bytes + 255) & ~(size_t)255;
    return p;
  };
  int*   deg     = (int*)walloc((size_t)N * 4);
  float* dinv    = (float*)walloc((size_t)N * 4);
  int*   startp  = (int*)walloc((size_t)N * 4);
  int*   cursor  = (int*)walloc((size_t)N * 4);
  int*   counter = (int*)walloc(256);
  int2*  csr     = (int2*)walloc((size_t)E * 8);
  u16*   A       = (u16*)walloc((size_t)N * D * 2);   // h (bf16)
  u16*   B       = (u16*)walloc((size_t)N * D * 2);   // y1 (bf16)
  u16*   Wt1     = (u16*)walloc((size_t)D * D * 2);
  u16*   Wt2     = (u16*)walloc((size_t)D * D * 2);
  float* O       = (float*)d_out;

  // ---- CSR build + weight prep ----
  hipMemsetAsync(deg, 0, (size_t)N * 4, stream);
  hipMemsetAsync(counter, 0, 4, stream);
  k_prep<<<(D * D + 255) / 256, 256, 0, stream>>>(W1, Wt1);
  k_prep<<<(D * D + 255) / 256, 256, 0, stream>>>(W2, Wt2);
  k_deg<<<(E + 255) / 256, 256, 0, stream>>>(dst, deg, E);
  k_dinv<<<(N + 255) / 256, 256, 0, stream>>>(deg, dinv, N);
  k_alloc<<<(N + 255) / 256, 256, 0, stream>>>(deg, startp, cursor, counter, N);
  k_fill<<<(E + 255) / 256, 256, 0, stream>>>(src, dst, dinv, cursor, csr, E);

  // ---- layer 1 ----
  k_gemm_mfma<false><<<(N + 63) / 64, 256, 0, stream>>>(x, Wt1, A, N);
  k_gather_ln<<<(N + 3) / 4, 256, 0, stream>>>((const u32*)A, startp, deg, dinv,
                                               csr, b1, g1, bl1, nullptr,
                                               nullptr, (u32*)B, N);
  // ---- layer 2 ----
  k_gemm_mfma<true><<<(N + 63) / 64, 256, 0, stream>>>(B, Wt2, A, N);
  k_gather_ln<<<(N + 3) / 4, 256, 0, stream>>>((const u32*)A, startp, deg, dinv,
                                               csr, b2, g2, bl2, x,
                                               O, nullptr, N);
}

// Round 4
// 251.820 us; speedup vs baseline: 8.8991x; 1.0681x over previous
//
#include <hip/hip_runtime.h>
#include <hip/hip_fp16.h>

#define D 128
#define EPS 1e-5f

typedef unsigned int u32;
typedef unsigned short u16;
typedef __attribute__((ext_vector_type(8))) _Float16 half8;  // mfma A/B frag
typedef __attribute__((ext_vector_type(4))) float f32x4;
typedef __attribute__((ext_vector_type(8))) u16 u16x8;
typedef __attribute__((ext_vector_type(4))) u16 u16x4;

__device__ inline u16 f2h(float x) {
  _Float16 t = (_Float16)x;
  return __builtin_bit_cast(u16, t);
}
__device__ inline __half2 b2h2(u32 u) { return __builtin_bit_cast(__half2, u); }

// ---------------------------------------------------------------------------
// CSR build
__global__ __launch_bounds__(256) void k_deg(const int* __restrict__ dst,
                                             int* __restrict__ deg, int E) {
  int i = blockIdx.x * 256 + threadIdx.x;
  if (i < E) atomicAdd(&deg[dst[i]], 1);
}

// deg -> dinv, and CSR range alloc (wave scan + one atomic per wave)
__global__ __launch_bounds__(256) void k_alloc(const int* __restrict__ deg,
                                               float* __restrict__ dinv,
                                               int* __restrict__ start,
                                               int* __restrict__ cursor,
                                               int* __restrict__ counter, int n) {
  int i = blockIdx.x * 256 + threadIdx.x;
  int lane = threadIdx.x & 63;
  int d = (i < n) ? deg[i] : 0;
  if (i < n) dinv[i] = rsqrtf((float)d + 1.0f);
  int v = d;
#pragma unroll
  for (int o = 1; o < 64; o <<= 1) {
    int t = __shfl_up(v, o, 64);
    if (lane >= o) v += t;
  }
  int total = __shfl(v, 63, 64);
  int base = 0;
  if (lane == 0) base = atomicAdd(counter, total);
  base = __shfl(base, 0, 64);
  if (i < n) {
    int st = base + v - d;
    start[i] = st;
    cursor[i] = st;
  }
}

// csr[pos] = {src, half2(w,w)}  with w = dinv[s]*dinv[d]
__global__ __launch_bounds__(256) void k_fill(const int* __restrict__ src,
                                              const int* __restrict__ dst,
                                              const float* __restrict__ dinv,
                                              int* __restrict__ cursor,
                                              int2* __restrict__ csr, int E) {
  int e = blockIdx.x * 256 + threadIdx.x;
  if (e >= E) return;
  int s = src[e], d = dst[e];
  int pos = atomicAdd(&cursor[d], 1);
  float w = dinv[s] * dinv[d];
  __half2 wh = __float2half2_rn(w);
  csr[pos] = make_int2(s, __builtin_bit_cast(int, wh));
}

// Both weights fp32[k][c] -> fp16 Wt[c][k] in one kernel.
__global__ __launch_bounds__(256) void k_prep(const float* __restrict__ W1,
                                              const float* __restrict__ W2,
                                              u16* __restrict__ Wt1,
                                              u16* __restrict__ Wt2) {
  int i = blockIdx.x * 256 + threadIdx.x;
  const float* W = (i < D * D) ? W1 : W2;
  u16* Wt = (i < D * D) ? Wt1 : Wt2;
  int ii = i & (D * D - 1);
  int k = ii >> 7, c = ii & 127;
  Wt[c * D + k] = f2h(W[ii]);
}

// ---------------------------------------------------------------------------
// MFMA GEMM: hb[r,:] = fp16( in[r,:] @ W )  via v_mfma_f32_16x16x32_f16.
// 64 rows/block, wave w covers rows w*16..w*16+15, all 128 cols.
// A-frag: A[m=lane&15][k=quad*8+j]; B from Wt[c][k] (contiguous 16B in k);
// D: col=lane&15, row=quad*4+reg.
template <bool F32IN>
__global__ __launch_bounds__(256) void k_gemm_mfma(const void* __restrict__ in_,
                                                   const u16* __restrict__ Wt,
                                                   u16* __restrict__ hb, int nrows) {
  __shared__ alignas(16) u16 sX[64 * 136];
  __shared__ alignas(16) u16 sW[128 * 136];
  const int tid = threadIdx.x;
  const int row0 = blockIdx.x * 64;

#pragma unroll
  for (int t = 0; t < 8; t++) {
    int f = tid + 256 * t;
    int r = f >> 4, c8 = f & 15;
    u16x8 w = *(const u16x8*)(Wt + r * D + c8 * 8);
    *(u16x8*)(sW + r * 136 + c8 * 8) = w;
  }
  if (F32IN) {
    const float* in = (const float*)in_;
#pragma unroll
    for (int t = 0; t < 8; t++) {
      int f = tid + 256 * t;
      int r = f >> 5, c4 = f & 31;
      float4 v = make_float4(0.f, 0.f, 0.f, 0.f);
      if (row0 + r < nrows) v = *(const float4*)(in + (size_t)(row0 + r) * D + c4 * 4);
      u16x4 p = {f2h(v.x), f2h(v.y), f2h(v.z), f2h(v.w)};
      *(u16x4*)(sX + r * 136 + c4 * 4) = p;
    }
  } else {
    const u16* in = (const u16*)in_;
#pragma unroll
    for (int t = 0; t < 4; t++) {
      int f = tid + 256 * t;
      int r = f >> 4, c8 = f & 15;
      u16x8 v = {};
      if (row0 + r < nrows) v = *(const u16x8*)(in + (size_t)(row0 + r) * D + c8 * 8);
      *(u16x8*)(sX + r * 136 + c8 * 8) = v;
    }
  }
  __syncthreads();

  const int lane = tid & 63, wv = tid >> 6;
  const int m = lane & 15, q = lane >> 4;
  const int r0 = wv * 16;

  f32x4 acc[8];
#pragma unroll
  for (int ct = 0; ct < 8; ct++) acc[ct] = (f32x4)(0.0f);

  const u16* ap = sX + (r0 + m) * 136 + q * 8;
  const u16* bp = sW + m * 136 + q * 8;
#pragma unroll
  for (int kk = 0; kk < 4; kk++) {
    half8 a = *(const half8*)(ap + kk * 32);
#pragma unroll
    for (int ct = 0; ct < 8; ct++) {
      half8 b = *(const half8*)(bp + ct * 16 * 136 + kk * 32);
      acc[ct] = __builtin_amdgcn_mfma_f32_16x16x32_f16(a, b, acc[ct], 0, 0, 0);
    }
  }

#pragma unroll
  for (int ct = 0; ct < 8; ct++) {
#pragma unroll
    for (int rg = 0; rg < 4; rg++) {
      int rr = row0 + r0 + q * 4 + rg;
      if (rr < nrows) hb[(size_t)rr * D + ct * 16 + m] = f2h(acc[ct][rg]);
    }
  }
}

// ---------------------------------------------------------------------------
// Fused CSR gather (fp16 h) + self-loop + bias + LayerNorm + ReLU (+residual).
// 2 rows per wave: 32 lanes per row, 4 cols (one uint2 = 2 half2) per lane.
// Every shfl / load / pk-fma instruction serves 2 edges.
__global__ __launch_bounds__(256) void k_gather_ln(
    const uint2* __restrict__ hb, const int* __restrict__ start,
    const int* __restrict__ deg, const float* __restrict__ dinv,
    const int2* __restrict__ csr,
    const float* __restrict__ b, const float* __restrict__ g,
    const float* __restrict__ bln, const float* __restrict__ resid,
    float* __restrict__ outf, uint2* __restrict__ outb, int n) {
  const int tid = threadIdx.x;
  const int sl = tid & 31;
  const int row = blockIdx.x * 8 + (tid >> 5);
  const bool valid = row < n;
  const int rc = valid ? row : 0;

  int beg = start[rc];
  int cnt = valid ? deg[rc] : 0;
  float dv = dinv[rc];
  __half2 sn2 = __float2half2_rn(dv * dv);

  uint2 su = hb[(size_t)rc * 32 + sl];
  __half2 acc0 = __hmul2(b2h2(su.x), sn2);
  __half2 acc1 = __hmul2(b2h2(su.y), sn2);

  int cmax = max(cnt, __shfl_xor(cnt, 32, 64));   // wave-uniform bound

  for (int j0 = 0; j0 < cmax; j0 += 32) {
    int m = cnt - j0;                 // edges left for this half (may be <=0)
    int se = 0, whb = 0;
    if (sl < m) {
      int2 pr = csr[beg + j0 + sl];
      se = pr.x;
      whb = pr.y;
    }
    int mm = min(cmax - j0, 32);      // wave-uniform trip count
    int j = 0;
    for (; j + 1 < mm; j += 2) {
      int s0 = __shfl(se, j, 32),  s1 = __shfl(se, j + 1, 32);
      int w0 = __shfl(whb, j, 32), w1 = __shfl(whb, j + 1, 32);
      uint2 v0 = make_uint2(0u, 0u), v1 = make_uint2(0u, 0u);
      if (j < m)     v0 = hb[(size_t)s0 * 32 + sl];
      if (j + 1 < m) v1 = hb[(size_t)s1 * 32 + sl];
      // unpredicated FMA is safe: masked lanes have v=0 and w=0 (0*0=0)
      acc0 = __hfma2(b2h2(v0.x), b2h2((u32)w0), acc0);
      acc1 = __hfma2(b2h2(v0.y), b2h2((u32)w0), acc1);
      acc0 = __hfma2(b2h2(v1.x), b2h2((u32)w1), acc0);
      acc1 = __hfma2(b2h2(v1.y), b2h2((u32)w1), acc1);
    }
    if (j < mm) {
      int s0 = __shfl(se, j, 32);
      int w0 = __shfl(whb, j, 32);
      uint2 v0 = make_uint2(0u, 0u);
      if (j < m) v0 = hb[(size_t)s0 * 32 + sl];
      acc0 = __hfma2(b2h2(v0.x), b2h2((u32)w0), acc0);
      acc1 = __hfma2(b2h2(v0.y), b2h2((u32)w0), acc1);
    }
  }

  // ---- LayerNorm over 128 cols spread 4-per-lane across 32 lanes ----
  float2 f0 = __half22float2(acc0);
  float2 f1 = __half22float2(acc1);
  int d0 = sl * 4;
  float4 bb = *(const float4*)(b + d0);
  float a0 = f0.x + bb.x, a1 = f0.y + bb.y;
  float a2 = f1.x + bb.z, a3 = f1.y + bb.w;

  float sum = a0 + a1 + a2 + a3;
#pragma unroll
  for (int o = 16; o >= 1; o >>= 1) sum += __shfl_xor(sum, o, 32);
  float mu = sum * (1.0f / 128.0f);
  float e0 = a0 - mu, e1 = a1 - mu, e2 = a2 - mu, e3 = a3 - mu;
  float vs = e0 * e0 + e1 * e1 + e2 * e2 + e3 * e3;
#pragma unroll
  for (int o = 16; o >= 1; o >>= 1) vs += __shfl_xor(vs, o, 32);
  float inv = rsqrtf(vs * (1.0f / 128.0f) + EPS);

  float4 gg = *(const float4*)(g + d0);
  float4 bl = *(const float4*)(bln + d0);
  float o0 = fmaxf(e0 * inv * gg.x + bl.x, 0.0f);
  float o1 = fmaxf(e1 * inv * gg.y + bl.y, 0.0f);
  float o2 = fmaxf(e2 * inv * gg.z + bl.z, 0.0f);
  float o3 = fmaxf(e3 * inv * gg.w + bl.w, 0.0f);

  if (!valid) return;
  if (outb) {
    uint2 pk;
    pk.x = ((u32)f2h(o1) << 16) | (u32)f2h(o0);
    pk.y = ((u32)f2h(o3) << 16) | (u32)f2h(o2);
    outb[(size_t)row * 32 + sl] = pk;
  } else {
    float4 rr = *(const float4*)(resid + (size_t)row * D + d0);
    *(float4*)(outf + (size_t)row * D + d0) =
        make_float4(o0 + rr.x, o1 + rr.y, o2 + rr.z, o3 + rr.w);
  }
}

// ---------------------------------------------------------------------------
extern "C" void kernel_launch(void* const* d_in, const int* in_sizes, int n_in,
                              void* d_out, int out_size, void* d_ws, size_t ws_size,
                              hipStream_t stream) {
  const float* x    = (const float*)d_in[0];
  const int*   ei   = (const int*)d_in[1];
  const float* W1   = (const float*)d_in[2];
  const float* b1   = (const float*)d_in[3];
  const float* g1   = (const float*)d_in[4];
  const float* bl1  = (const float*)d_in[5];
  const float* W2   = (const float*)d_in[6];
  const float* b2   = (const float*)d_in[7];
  const float* g2   = (const float*)d_in[8];
  const float* bl2  = (const float*)d_in[9];

  const int N = in_sizes[0] / D;
  const int E = in_sizes[1] / 2;
  const int* src = ei;
  const int* dst = ei + E;

  size_t off = 0;
  auto walloc = [&](size_t bytes) {
    void* p = (char*)d_ws + off;
    off = (off + bytes + 255) & ~(size_t)255;
    return p;
  };
  int*   deg     = (int*)walloc((size_t)N * 4);
  float* dinv    = (float*)walloc((size_t)N * 4);
  int*   startp  = (int*)walloc((size_t)N * 4);
  int*   cursor  = (int*)walloc((size_t)N * 4);
  int*   counter = (int*)walloc(256);
  int2*  csr     = (int2*)walloc((size_t)E * 8);
  u16*   A       = (u16*)walloc((size_t)N * D * 2);   // h (fp16)
  u16*   B       = (u16*)walloc((size_t)N * D * 2);   // y1 (fp16)
  u16*   Wt1     = (u16*)walloc((size_t)D * D * 2);
  u16*   Wt2     = (u16*)walloc((size_t)D * D * 2);
  float* O       = (float*)d_out;

  // ---- CSR build + weight prep ----
  hipMemsetAsync(deg, 0, (size_t)N * 4, stream);
  hipMemsetAsync(counter, 0, 4, stream);
  k_prep<<<(2 * D * D + 255) / 256, 256, 0, stream>>>(W1, W2, Wt1, Wt2);
  k_deg<<<(E + 255) / 256, 256, 0, stream>>>(dst, deg, E);
  k_alloc<<<(N + 255) / 256, 256, 0, stream>>>(deg, dinv, startp, cursor, counter, N);
  k_fill<<<(E + 255) / 256, 256, 0, stream>>>(src, dst, dinv, cursor, csr, E);

  // ---- layer 1 ----
  k_gemm_mfma<true><<<(N + 63) / 64, 256, 0, stream>>>(x, Wt1, A, N);
  k_gather_ln<<<(N + 7) / 8, 256, 0, stream>>>((const uint2*)A, startp, deg, dinv,
                                               csr, b1, g1, bl1, nullptr,
                                               nullptr, (uint2*)B, N);
  // ---- layer 2 ----
  k_gemm_mfma<false><<<(N + 63) / 64, 256, 0, stream>>>(B, Wt2, A, N);
  k_gather_ln<<<(N + 7) / 8, 256, 0, stream>>>((const uint2*)A, startp, deg, dinv,
                                               csr, b2, g2, bl2, x,
                                               O, nullptr, N);
}

// Round 5
// 250.612 us; speedup vs baseline: 8.9420x; 1.0048x over previous
//
#include <hip/hip_runtime.h>
#include <hip/hip_fp16.h>

#define D 128
#define EPS 1e-5f

typedef unsigned int u32;
typedef unsigned short u16;
typedef __attribute__((ext_vector_type(8))) _Float16 half8;  // mfma A/B frag
typedef __attribute__((ext_vector_type(4))) float f32x4;

__device__ inline u16 f2h(float x) {
  _Float16 t = (_Float16)x;
  return __builtin_bit_cast(u16, t);
}
__device__ inline __half2 b2h2(u32 u) { return __builtin_bit_cast(__half2, u); }

// ---------------------------------------------------------------------------
// P0: zero deg + counter, convert W1,W2 fp32[k][c] -> fp16 Wt[c][k].
__global__ __launch_bounds__(256) void k_prep(const float* __restrict__ W1,
                                              const float* __restrict__ W2,
                                              u16* __restrict__ Wt1,
                                              u16* __restrict__ Wt2,
                                              int* __restrict__ deg,
                                              int* __restrict__ counter, int n) {
  int i = blockIdx.x * 256 + threadIdx.x;
  if (i < n) deg[i] = 0;
  if (i == 0) *counter = 0;
  if (i < 2 * D * D) {
    const float* W = (i < D * D) ? W1 : W2;
    u16* Wt = (i < D * D) ? Wt1 : Wt2;
    int ii = i & (D * D - 1);
    int k = ii >> 7, c = ii & 127;
    Wt[c * D + k] = f2h(W[ii]);
  }
}

// P1: degree histogram.
__global__ __launch_bounds__(256) void k_deg(const int* __restrict__ dst,
                                             int* __restrict__ deg, int E) {
  int i = blockIdx.x * 256 + threadIdx.x;
  if (i < E) atomicAdd(&deg[dst[i]], 1);
}

// P2: dinv + CSR range alloc; meta[i] = {start, deg, dinv_bits, 0}.
__global__ __launch_bounds__(256) void k_alloc(const int* __restrict__ deg,
                                               float* __restrict__ dinv,
                                               int4* __restrict__ meta,
                                               int* __restrict__ cursor,
                                               int* __restrict__ counter, int n) {
  int i = blockIdx.x * 256 + threadIdx.x;
  int lane = threadIdx.x & 63;
  int d = (i < n) ? deg[i] : 0;
  float dv = rsqrtf((float)d + 1.0f);
  int v = d;
#pragma unroll
  for (int o = 1; o < 64; o <<= 1) {
    int t = __shfl_up(v, o, 64);
    if (lane >= o) v += t;
  }
  int total = __shfl(v, 63, 64);
  int base = 0;
  if (lane == 0) base = atomicAdd(counter, total);
  base = __shfl(base, 0, 64);
  if (i < n) {
    int st = base + v - d;
    dinv[i] = dv;
    meta[i] = make_int4(st, d, __builtin_bit_cast(int, dv), 0);
    cursor[i] = st;
  }
}

// ---------------------------------------------------------------------------
// LDS-free MFMA GEMM body: out[r,:] = fp16( in[r,:] @ W ), 64 rows per block
// (wave wv covers rows wv*16..+15). A-frag: lane(m,q) = A[row0+m][k=q*8+j],
// contiguous 16B in k from global. B-frag from Wt[c][k] (L2-hot 32KB).
// D-layout: col = ct*16 + (lane&15), row = quad*4 + reg.
template <bool F32IN>
__device__ __forceinline__ void gemm_body(const void* __restrict__ in_,
                                          const u16* __restrict__ Wt,
                                          u16* __restrict__ out, int nrows,
                                          int blk) {
  const int tid = threadIdx.x;
  const int lane = tid & 63, wv = tid >> 6;
  const int m = lane & 15, q = lane >> 4;
  const int r0 = blk * 64 + wv * 16;
  const int rowa = min(r0 + m, nrows - 1);

  f32x4 acc[8];
#pragma unroll
  for (int ct = 0; ct < 8; ct++) acc[ct] = (f32x4)(0.0f);

#pragma unroll
  for (int kk = 0; kk < 4; kk++) {
    const int kbase = kk * 32 + q * 8;
    half8 a;
    if (F32IN) {
      const float* in = (const float*)in_;
      float4 v0 = *(const float4*)(in + (size_t)rowa * D + kbase);
      float4 v1 = *(const float4*)(in + (size_t)rowa * D + kbase + 4);
      a[0] = (_Float16)v0.x; a[1] = (_Float16)v0.y;
      a[2] = (_Float16)v0.z; a[3] = (_Float16)v0.w;
      a[4] = (_Float16)v1.x; a[5] = (_Float16)v1.y;
      a[6] = (_Float16)v1.z; a[7] = (_Float16)v1.w;
    } else {
      const u16* in = (const u16*)in_;
      a = *(const half8*)(in + (size_t)rowa * D + kbase);
    }
#pragma unroll
    for (int ct = 0; ct < 8; ct++) {
      half8 b = *(const half8*)(Wt + (ct * 16 + m) * D + kbase);
      acc[ct] = __builtin_amdgcn_mfma_f32_16x16x32_f16(a, b, acc[ct], 0, 0, 0);
    }
  }

#pragma unroll
  for (int ct = 0; ct < 8; ct++) {
#pragma unroll
    for (int rg = 0; rg < 4; rg++) {
      int rr = r0 + q * 4 + rg;
      if (rr < nrows) out[(size_t)rr * D + ct * 16 + m] = f2h(acc[ct][rg]);
    }
  }
}

// P3: CSR fill (blocks [0,FB)) overlapped with GEMM1 (blocks [FB,FB+GB)).
__global__ __launch_bounds__(256) void k_fill_gemm1(
    const int* __restrict__ src, const int* __restrict__ dst,
    const float* __restrict__ dinv, int* __restrict__ cursor,
    u32* __restrict__ csr, int E, int FB,
    const float* __restrict__ x, const u16* __restrict__ Wt1,
    u16* __restrict__ A, int nrows) {
  if (blockIdx.x < (u32)FB) {
    int e = blockIdx.x * 256 + threadIdx.x;
    if (e < E) {
      int s = src[e], d = dst[e];
      int pos = atomicAdd(&cursor[d], 1);
      float w = dinv[s] * dinv[d];
      csr[pos] = (u32)s | ((u32)f2h(w) << 16);    // src:16 | w:fp16
    }
  } else {
    gemm_body<true>(x, Wt1, A, nrows, blockIdx.x - FB);
  }
}

// P5: standalone GEMM2 (fp16 input).
__global__ __launch_bounds__(256) void k_gemm2(const u16* __restrict__ in,
                                               const u16* __restrict__ Wt,
                                               u16* __restrict__ out, int nrows) {
  gemm_body<false>(in, Wt, out, nrows, blockIdx.x);
}

// ---------------------------------------------------------------------------
// P4/P6: fused CSR gather (fp16 h) + self-loop + bias + LN + ReLU (+residual).
// 2 rows per wave, 32 lanes per row, uint2 (4 fp16) per lane.
// Branch-free unroll-4 inner loop: padded entries are e=0 (src 0, w +0).
__global__ __launch_bounds__(256) void k_gather_ln(
    const uint2* __restrict__ hb, const int4* __restrict__ meta,
    const u32* __restrict__ csr,
    const float* __restrict__ b, const float* __restrict__ g,
    const float* __restrict__ bln, const float* __restrict__ resid,
    float* __restrict__ outf, uint2* __restrict__ outb, int n) {
  const int tid = threadIdx.x;
  const int sl = tid & 31;
  const int row = blockIdx.x * 8 + (tid >> 5);
  const bool valid = row < n;
  const int rc = valid ? row : 0;

  int4 mt = meta[rc];
  int beg = mt.x;
  int cnt = valid ? mt.y : 0;
  float dv = __builtin_bit_cast(float, mt.z);
  __half2 sn2 = __float2half2_rn(dv * dv);

  uint2 su = hb[(size_t)rc * 32 + sl];
  __half2 acc0 = __hmul2(b2h2(su.x), sn2);
  __half2 acc1 = __hmul2(b2h2(su.y), sn2);

  int cmax = max(cnt, __shfl_xor(cnt, 32, 64));   // wave-uniform bound

  for (int j0 = 0; j0 < cmax; j0 += 32) {
    u32 e = 0u;
    if (sl < cnt - j0) e = csr[beg + j0 + sl];    // lanes past cnt hold e=0
    int mm = min(cmax - j0, 32);
    // j in {0,4,...}; j <= 28 so broadcast index j+3 <= 31 always; lanes in
    // [cnt-j0,32) have e=0 => w=0, src=0 (harmless hot load of row 0).
    for (int j = 0; j < mm; j += 4) {
      u32 e0 = __shfl(e, j, 32),     e1 = __shfl(e, j + 1, 32);
      u32 e2 = __shfl(e, j + 2, 32), e3 = __shfl(e, j + 3, 32);
      uint2 v0 = hb[(size_t)(e0 & 0xffffu) * 32 + sl];
      uint2 v1 = hb[(size_t)(e1 & 0xffffu) * 32 + sl];
      uint2 v2 = hb[(size_t)(e2 & 0xffffu) * 32 + sl];
      uint2 v3 = hb[(size_t)(e3 & 0xffffu) * 32 + sl];
      __half2 w0 = b2h2((e0 >> 16) | (e0 & 0xffff0000u));
      __half2 w1 = b2h2((e1 >> 16) | (e1 & 0xffff0000u));
      __half2 w2 = b2h2((e2 >> 16) | (e2 & 0xffff0000u));
      __half2 w3 = b2h2((e3 >> 16) | (e3 & 0xffff0000u));
      acc0 = __hfma2(b2h2(v0.x), w0, acc0);
      acc1 = __hfma2(b2h2(v0.y), w0, acc1);
      acc0 = __hfma2(b2h2(v1.x), w1, acc0);
      acc1 = __hfma2(b2h2(v1.y), w1, acc1);
      acc0 = __hfma2(b2h2(v2.x), w2, acc0);
      acc1 = __hfma2(b2h2(v2.y), w2, acc1);
      acc0 = __hfma2(b2h2(v3.x), w3, acc0);
      acc1 = __hfma2(b2h2(v3.y), w3, acc1);
    }
  }

  // ---- LayerNorm over 128 cols, 4 per lane across 32 lanes ----
  float2 f0 = __half22float2(acc0);
  float2 f1 = __half22float2(acc1);
  int d0 = sl * 4;
  float4 bb = *(const float4*)(b + d0);
  float a0 = f0.x + bb.x, a1 = f0.y + bb.y;
  float a2 = f1.x + bb.z, a3 = f1.y + bb.w;

  float sum = a0 + a1 + a2 + a3;
#pragma unroll
  for (int o = 16; o >= 1; o >>= 1) sum += __shfl_xor(sum, o, 32);
  float mu = sum * (1.0f / 128.0f);
  float e0 = a0 - mu, e1 = a1 - mu, e2 = a2 - mu, e3 = a3 - mu;
  float vs = e0 * e0 + e1 * e1 + e2 * e2 + e3 * e3;
#pragma unroll
  for (int o = 16; o >= 1; o >>= 1) vs += __shfl_xor(vs, o, 32);
  float inv = rsqrtf(vs * (1.0f / 128.0f) + EPS);

  float4 gg = *(const float4*)(g + d0);
  float4 bl = *(const float4*)(bln + d0);
  float o0 = fmaxf(e0 * inv * gg.x + bl.x, 0.0f);
  float o1 = fmaxf(e1 * inv * gg.y + bl.y, 0.0f);
  float o2 = fmaxf(e2 * inv * gg.z + bl.z, 0.0f);
  float o3 = fmaxf(e3 * inv * gg.w + bl.w, 0.0f);

  if (!valid) return;
  if (outb) {
    uint2 pk;
    pk.x = ((u32)f2h(o1) << 16) | (u32)f2h(o0);
    pk.y = ((u32)f2h(o3) << 16) | (u32)f2h(o2);
    outb[(size_t)row * 32 + sl] = pk;
  } else {
    float4 rr = *(const float4*)(resid + (size_t)row * D + d0);
    *(float4*)(outf + (size_t)row * D + d0) =
        make_float4(o0 + rr.x, o1 + rr.y, o2 + rr.z, o3 + rr.w);
  }
}

// ---------------------------------------------------------------------------
extern "C" void kernel_launch(void* const* d_in, const int* in_sizes, int n_in,
                              void* d_out, int out_size, void* d_ws, size_t ws_size,
                              hipStream_t stream) {
  const float* x    = (const float*)d_in[0];
  const int*   ei   = (const int*)d_in[1];
  const float* W1   = (const float*)d_in[2];
  const float* b1   = (const float*)d_in[3];
  const float* g1   = (const float*)d_in[4];
  const float* bl1  = (const float*)d_in[5];
  const float* W2   = (const float*)d_in[6];
  const float* b2   = (const float*)d_in[7];
  const float* g2   = (const float*)d_in[8];
  const float* bl2  = (const float*)d_in[9];

  const int N = in_sizes[0] / D;
  const int E = in_sizes[1] / 2;
  const int* src = ei;
  const int* dst = ei + E;

  size_t off = 0;
  auto walloc = [&](size_t bytes) {
    void* p = (char*)d_ws + off;
    off = (off + bytes + 255) & ~(size_t)255;
    return p;
  };
  int*   deg     = (int*)walloc((size_t)N * 4);
  float* dinv    = (float*)walloc((size_t)N * 4);
  int4*  meta    = (int4*)walloc((size_t)N * 16);
  int*   cursor  = (int*)walloc((size_t)N * 4);
  int*   counter = (int*)walloc(256);
  u32*   csr     = (u32*)walloc((size_t)E * 4);
  u16*   A       = (u16*)walloc((size_t)N * D * 2);   // h (fp16)
  u16*   B       = (u16*)walloc((size_t)N * D * 2);   // y1 (fp16)
  u16*   Wt1     = (u16*)walloc((size_t)D * D * 2);
  u16*   Wt2     = (u16*)walloc((size_t)D * D * 2);
  float* O       = (float*)d_out;

  const int FB = (E + 255) / 256;        // fill blocks
  const int GB = (N + 63) / 64;          // gemm blocks

  // P0: prep (zero deg/counter + both weight converts)
  int p0 = max(N, 2 * D * D);
  k_prep<<<(p0 + 255) / 256, 256, 0, stream>>>(W1, W2, Wt1, Wt2, deg, counter, N);
  // P1: degrees
  k_deg<<<FB, 256, 0, stream>>>(dst, deg, E);
  // P2: alloc (dinv + meta + cursor)
  k_alloc<<<(N + 255) / 256, 256, 0, stream>>>(deg, dinv, meta, cursor, counter, N);
  // P3: CSR fill || GEMM1 (x @ W1 -> A)
  k_fill_gemm1<<<FB + GB, 256, 0, stream>>>(src, dst, dinv, cursor, csr, E, FB,
                                            x, Wt1, A, N);
  // P4: gather + LN + ReLU -> B (fp16)
  k_gather_ln<<<(N + 7) / 8, 256, 0, stream>>>((const uint2*)A, meta, csr,
                                               b1, g1, bl1, nullptr,
                                               nullptr, (uint2*)B, N);
  // P5: GEMM2 (B @ W2 -> A)
  k_gemm2<<<GB, 256, 0, stream>>>(B, Wt2, A, N);
  // P6: gather + LN + ReLU + residual -> O (fp32)
  k_gather_ln<<<(N + 7) / 8, 256, 0, stream>>>((const uint2*)A, meta, csr,
                                               b2, g2, bl2, x,
                                               O, nullptr, N);
}

// Round 6
// 232.229 us; speedup vs baseline: 9.6498x; 1.0792x over previous
//
#include <hip/hip_runtime.h>
#include <hip/hip_fp16.h>

#define D 128
#define EPS 1e-5f

typedef unsigned int u32;
typedef unsigned short u16;
typedef __attribute__((ext_vector_type(8))) _Float16 half8;  // mfma A/B frag
typedef __attribute__((ext_vector_type(4))) float f32x4;

__device__ inline u16 f2h(float x) {
  _Float16 t = (_Float16)x;
  return __builtin_bit_cast(u16, t);
}
__device__ inline __half2 b2h2(u32 u) { return __builtin_bit_cast(__half2, u); }

// ---------------------------------------------------------------------------
// P0: zero deg + counter, convert W1,W2 fp32[k][c] -> fp16 Wt[c][k].
__global__ __launch_bounds__(256) void k_prep(const float* __restrict__ W1,
                                              const float* __restrict__ W2,
                                              u16* __restrict__ Wt1,
                                              u16* __restrict__ Wt2,
                                              int* __restrict__ deg,
                                              int* __restrict__ counter, int n) {
  int i = blockIdx.x * 256 + threadIdx.x;
  if (i < n) deg[i] = 0;
  if (i == 0) *counter = 0;
  if (i < 2 * D * D) {
    const float* W = (i < D * D) ? W1 : W2;
    u16* Wt = (i < D * D) ? Wt1 : Wt2;
    int ii = i & (D * D - 1);
    int k = ii >> 7, c = ii & 127;
    Wt[c * D + k] = f2h(W[ii]);
  }
}

// ---------------------------------------------------------------------------
// LDS-free MFMA GEMM body: out[r,:] = fp16( in[r,:] @ W ), 64 rows per block
// (wave wv covers rows wv*16..+15). A-frag: lane(m,q) = A[row0+m][k=q*8+j],
// contiguous 16B in k from global. B-frag from Wt[c][k] (L2-hot 32KB).
// D-layout: col = ct*16 + (lane&15), row = quad*4 + reg.
template <bool F32IN>
__device__ __forceinline__ void gemm_body(const void* __restrict__ in_,
                                          const u16* __restrict__ Wt,
                                          u16* __restrict__ out, int nrows,
                                          int blk) {
  const int tid = threadIdx.x;
  const int lane = tid & 63, wv = tid >> 6;
  const int m = lane & 15, q = lane >> 4;
  const int r0 = blk * 64 + wv * 16;
  const int rowa = min(r0 + m, nrows - 1);

  f32x4 acc[8];
#pragma unroll
  for (int ct = 0; ct < 8; ct++) acc[ct] = (f32x4)(0.0f);

#pragma unroll
  for (int kk = 0; kk < 4; kk++) {
    const int kbase = kk * 32 + q * 8;
    half8 a;
    if (F32IN) {
      const float* in = (const float*)in_;
      float4 v0 = *(const float4*)(in + (size_t)rowa * D + kbase);
      float4 v1 = *(const float4*)(in + (size_t)rowa * D + kbase + 4);
      a[0] = (_Float16)v0.x; a[1] = (_Float16)v0.y;
      a[2] = (_Float16)v0.z; a[3] = (_Float16)v0.w;
      a[4] = (_Float16)v1.x; a[5] = (_Float16)v1.y;
      a[6] = (_Float16)v1.z; a[7] = (_Float16)v1.w;
    } else {
      const u16* in = (const u16*)in_;
      a = *(const half8*)(in + (size_t)rowa * D + kbase);
    }
#pragma unroll
    for (int ct = 0; ct < 8; ct++) {
      half8 b = *(const half8*)(Wt + (ct * 16 + m) * D + kbase);
      acc[ct] = __builtin_amdgcn_mfma_f32_16x16x32_f16(a, b, acc[ct], 0, 0, 0);
    }
  }

#pragma unroll
  for (int ct = 0; ct < 8; ct++) {
#pragma unroll
    for (int rg = 0; rg < 4; rg++) {
      int rr = r0 + q * 4 + rg;
      if (rr < nrows) out[(size_t)rr * D + ct * 16 + m] = f2h(acc[ct][rg]);
    }
  }
}

// P1: deg histogram + per-edge rank (blocks [0,DB)) || GEMM1 (blocks >= DB).
// atomicAdd's return value IS the rank of edge e within its dst bucket.
__global__ __launch_bounds__(256) void k_deg_gemm1(
    const int* __restrict__ dst, int* __restrict__ deg, int* __restrict__ rank,
    int E, int DB,
    const float* __restrict__ x, const u16* __restrict__ Wt1,
    u16* __restrict__ A, int nrows) {
  if (blockIdx.x < (u32)DB) {
    int e = blockIdx.x * 256 + threadIdx.x;
    if (e < E) rank[e] = atomicAdd(&deg[dst[e]], 1);
  } else {
    gemm_body<true>(x, Wt1, A, nrows, blockIdx.x - DB);
  }
}

// P2: dinv + CSR range alloc; meta[i] = {start, deg, dinv_bits, 0}.
__global__ __launch_bounds__(256) void k_alloc(const int* __restrict__ deg,
                                               float* __restrict__ dinv,
                                               int4* __restrict__ meta,
                                               int* __restrict__ startp,
                                               int* __restrict__ counter, int n) {
  int i = blockIdx.x * 256 + threadIdx.x;
  int lane = threadIdx.x & 63;
  int d = (i < n) ? deg[i] : 0;
  float dv = rsqrtf((float)d + 1.0f);
  int v = d;
#pragma unroll
  for (int o = 1; o < 64; o <<= 1) {
    int t = __shfl_up(v, o, 64);
    if (lane >= o) v += t;
  }
  int total = __shfl(v, 63, 64);
  int base = 0;
  if (lane == 0) base = atomicAdd(counter, total);
  base = __shfl(base, 0, 64);
  if (i < n) {
    int st = base + v - d;
    dinv[i] = dv;
    meta[i] = make_int4(st, d, __builtin_bit_cast(int, dv), 0);
    startp[i] = st;
  }
}

// P3: CSR fill, atomic-free: pos = start[d] + rank[e].
__global__ __launch_bounds__(256) void k_fill(
    const int* __restrict__ src, const int* __restrict__ dst,
    const int* __restrict__ rank, const int* __restrict__ startp,
    const float* __restrict__ dinv, u32* __restrict__ csr, int E) {
  int e = blockIdx.x * 256 + threadIdx.x;
  if (e >= E) return;
  int s = src[e], d = dst[e];
  int pos = startp[d] + rank[e];
  float w = dinv[s] * dinv[d];
  csr[pos] = (u32)s | ((u32)f2h(w) << 16);     // src:16 | w:fp16
}

// P5: standalone GEMM2 (fp16 input).
__global__ __launch_bounds__(256) void k_gemm2(const u16* __restrict__ in,
                                               const u16* __restrict__ Wt,
                                               u16* __restrict__ out, int nrows) {
  gemm_body<false>(in, Wt, out, nrows, blockIdx.x);
}

// ---------------------------------------------------------------------------
// P4/P6: fused CSR gather (fp16 h) + self-loop + bias + LN + ReLU (+residual).
// 4 rows per wave: 16 lanes per row, uint4 (8 fp16) per lane covers the 256B
// row. Unroll-4 => 16 edge-row loads in flight per wave. Branch-free body:
// padded entries are e=0 (src 0, w +0).
__global__ __launch_bounds__(256) void k_gather_ln(
    const uint4* __restrict__ hb, const int4* __restrict__ meta,
    const u32* __restrict__ csr,
    const float* __restrict__ b, const float* __restrict__ g,
    const float* __restrict__ bln, const float* __restrict__ resid,
    float* __restrict__ outf, uint4* __restrict__ outb, int n) {
  const int tid = threadIdx.x;
  const int sl = tid & 15;                     // lane within row-group
  const int row = blockIdx.x * 16 + (tid >> 4);
  const bool valid = row < n;
  const int rc = valid ? row : 0;

  int4 mt = meta[rc];
  int beg = mt.x;
  int cnt = valid ? mt.y : 0;
  float dv = __builtin_bit_cast(float, mt.z);
  __half2 sn2 = __float2half2_rn(dv * dv);

  uint4 su = hb[(size_t)rc * 16 + sl];
  __half2 acc0 = __hmul2(b2h2(su.x), sn2);
  __half2 acc1 = __hmul2(b2h2(su.y), sn2);
  __half2 acc2 = __hmul2(b2h2(su.z), sn2);
  __half2 acc3 = __hmul2(b2h2(su.w), sn2);

  // wave-uniform bound = max cnt over the wave's 4 row-groups
  int cm = max(cnt, __shfl_xor(cnt, 16, 64));
  cm = max(cm, __shfl_xor(cm, 32, 64));

  for (int j0 = 0; j0 < cm; j0 += 16) {
    u32 e = 0u;
    if (sl < cnt - j0) e = csr[beg + j0 + sl];  // lanes past cnt hold e=0
    int mm = min(cm - j0, 16);
    // j <= 12 so segment-broadcast index j+3 <= 15; e=0 lanes => w=0, src=0
    // (harmless hot load of row 0).
    for (int j = 0; j < mm; j += 4) {
      u32 e0 = __shfl(e, j, 16),     e1 = __shfl(e, j + 1, 16);
      u32 e2 = __shfl(e, j + 2, 16), e3 = __shfl(e, j + 3, 16);
      uint4 v0 = hb[(size_t)(e0 & 0xffffu) * 16 + sl];
      uint4 v1 = hb[(size_t)(e1 & 0xffffu) * 16 + sl];
      uint4 v2 = hb[(size_t)(e2 & 0xffffu) * 16 + sl];
      uint4 v3 = hb[(size_t)(e3 & 0xffffu) * 16 + sl];
      __half2 w0 = b2h2((e0 >> 16) | (e0 & 0xffff0000u));
      __half2 w1 = b2h2((e1 >> 16) | (e1 & 0xffff0000u));
      __half2 w2 = b2h2((e2 >> 16) | (e2 & 0xffff0000u));
      __half2 w3 = b2h2((e3 >> 16) | (e3 & 0xffff0000u));
      acc0 = __hfma2(b2h2(v0.x), w0, acc0);
      acc1 = __hfma2(b2h2(v0.y), w0, acc1);
      acc2 = __hfma2(b2h2(v0.z), w0, acc2);
      acc3 = __hfma2(b2h2(v0.w), w0, acc3);
      acc0 = __hfma2(b2h2(v1.x), w1, acc0);
      acc1 = __hfma2(b2h2(v1.y), w1, acc1);
      acc2 = __hfma2(b2h2(v1.z), w1, acc2);
      acc3 = __hfma2(b2h2(v1.w), w1, acc3);
      acc0 = __hfma2(b2h2(v2.x), w2, acc0);
      acc1 = __hfma2(b2h2(v2.y), w2, acc1);
      acc2 = __hfma2(b2h2(v2.z), w2, acc2);
      acc3 = __hfma2(b2h2(v2.w), w2, acc3);
      acc0 = __hfma2(b2h2(v3.x), w3, acc0);
      acc1 = __hfma2(b2h2(v3.y), w3, acc1);
      acc2 = __hfma2(b2h2(v3.z), w3, acc2);
      acc3 = __hfma2(b2h2(v3.w), w3, acc3);
    }
  }

  // ---- LayerNorm over 128 cols, 8 per lane across 16 lanes ----
  float2 f0 = __half22float2(acc0);
  float2 f1 = __half22float2(acc1);
  float2 f2 = __half22float2(acc2);
  float2 f3 = __half22float2(acc3);
  int d0 = sl * 8;
  float4 bb0 = *(const float4*)(b + d0);
  float4 bb1 = *(const float4*)(b + d0 + 4);
  float a0 = f0.x + bb0.x, a1 = f0.y + bb0.y;
  float a2 = f1.x + bb0.z, a3 = f1.y + bb0.w;
  float a4 = f2.x + bb1.x, a5 = f2.y + bb1.y;
  float a6 = f3.x + bb1.z, a7 = f3.y + bb1.w;

  float sum = ((a0 + a1) + (a2 + a3)) + ((a4 + a5) + (a6 + a7));
#pragma unroll
  for (int o = 8; o >= 1; o >>= 1) sum += __shfl_xor(sum, o, 16);
  float mu = sum * (1.0f / 128.0f);
  float e0 = a0 - mu, e1 = a1 - mu, e2 = a2 - mu, e3 = a3 - mu;
  float e4 = a4 - mu, e5 = a5 - mu, e6 = a6 - mu, e7 = a7 - mu;
  float vs = ((e0 * e0 + e1 * e1) + (e2 * e2 + e3 * e3)) +
             ((e4 * e4 + e5 * e5) + (e6 * e6 + e7 * e7));
#pragma unroll
  for (int o = 8; o >= 1; o >>= 1) vs += __shfl_xor(vs, o, 16);
  float inv = rsqrtf(vs * (1.0f / 128.0f) + EPS);

  float4 gg0 = *(const float4*)(g + d0);
  float4 gg1 = *(const float4*)(g + d0 + 4);
  float4 bl0 = *(const float4*)(bln + d0);
  float4 bl1 = *(const float4*)(bln + d0 + 4);
  float o0 = fmaxf(e0 * inv * gg0.x + bl0.x, 0.0f);
  float o1 = fmaxf(e1 * inv * gg0.y + bl0.y, 0.0f);
  float o2 = fmaxf(e2 * inv * gg0.z + bl0.z, 0.0f);
  float o3 = fmaxf(e3 * inv * gg0.w + bl0.w, 0.0f);
  float o4 = fmaxf(e4 * inv * gg1.x + bl1.x, 0.0f);
  float o5 = fmaxf(e5 * inv * gg1.y + bl1.y, 0.0f);
  float o6 = fmaxf(e6 * inv * gg1.z + bl1.z, 0.0f);
  float o7 = fmaxf(e7 * inv * gg1.w + bl1.w, 0.0f);

  if (!valid) return;
  if (outb) {
    uint4 pk;
    pk.x = ((u32)f2h(o1) << 16) | (u32)f2h(o0);
    pk.y = ((u32)f2h(o3) << 16) | (u32)f2h(o2);
    pk.z = ((u32)f2h(o5) << 16) | (u32)f2h(o4);
    pk.w = ((u32)f2h(o7) << 16) | (u32)f2h(o6);
    outb[(size_t)row * 16 + sl] = pk;
  } else {
    size_t base = (size_t)row * D + d0;
    float4 r0 = *(const float4*)(resid + base);
    float4 r1 = *(const float4*)(resid + base + 4);
    *(float4*)(outf + base) =
        make_float4(o0 + r0.x, o1 + r0.y, o2 + r0.z, o3 + r0.w);
    *(float4*)(outf + base + 4) =
        make_float4(o4 + r1.x, o5 + r1.y, o6 + r1.z, o7 + r1.w);
  }
}

// ---------------------------------------------------------------------------
extern "C" void kernel_launch(void* const* d_in, const int* in_sizes, int n_in,
                              void* d_out, int out_size, void* d_ws, size_t ws_size,
                              hipStream_t stream) {
  const float* x    = (const float*)d_in[0];
  const int*   ei   = (const int*)d_in[1];
  const float* W1   = (const float*)d_in[2];
  const float* b1   = (const float*)d_in[3];
  const float* g1   = (const float*)d_in[4];
  const float* bl1  = (const float*)d_in[5];
  const float* W2   = (const float*)d_in[6];
  const float* b2   = (const float*)d_in[7];
  const float* g2   = (const float*)d_in[8];
  const float* bl2  = (const float*)d_in[9];

  const int N = in_sizes[0] / D;
  const int E = in_sizes[1] / 2;
  const int* src = ei;
  const int* dst = ei + E;

  size_t off = 0;
  auto walloc = [&](size_t bytes) {
    void* p = (char*)d_ws + off;
    off = (off + bytes + 255) & ~(size_t)255;
    return p;
  };
  int*   deg     = (int*)walloc((size_t)N * 4);
  float* dinv    = (float*)walloc((size_t)N * 4);
  int4*  meta    = (int4*)walloc((size_t)N * 16);
  int*   startp  = (int*)walloc((size_t)N * 4);
  int*   counter = (int*)walloc(256);
  int*   rank    = (int*)walloc((size_t)E * 4);
  u32*   csr     = (u32*)walloc((size_t)E * 4);
  u16*   A       = (u16*)walloc((size_t)N * D * 2);   // h (fp16)
  u16*   B       = (u16*)walloc((size_t)N * D * 2);   // y1 (fp16)
  u16*   Wt1     = (u16*)walloc((size_t)D * D * 2);
  u16*   Wt2     = (u16*)walloc((size_t)D * D * 2);
  float* O       = (float*)d_out;

  const int DB = (E + 255) / 256;        // deg/fill blocks
  const int GB = (N + 63) / 64;          // gemm blocks

  // P0: prep (zero deg/counter + both weight converts)
  int p0 = max(N, 2 * D * D);
  k_prep<<<(p0 + 255) / 256, 256, 0, stream>>>(W1, W2, Wt1, Wt2, deg, counter, N);
  // P1: degrees + ranks || GEMM1 (x @ W1 -> A)
  k_deg_gemm1<<<DB + GB, 256, 0, stream>>>(dst, deg, rank, E, DB, x, Wt1, A, N);
  // P2: alloc (dinv + meta + startp)
  k_alloc<<<(N + 255) / 256, 256, 0, stream>>>(deg, dinv, meta, startp, counter, N);
  // P3: CSR fill (atomic-free)
  k_fill<<<DB, 256, 0, stream>>>(src, dst, rank, startp, dinv, csr, E);
  // P4: gather + LN + ReLU -> B (fp16)
  k_gather_ln<<<(N + 15) / 16, 256, 0, stream>>>((const uint4*)A, meta, csr,
                                                 b1, g1, bl1, nullptr,
                                                 nullptr, (uint4*)B, N);
  // P5: GEMM2 (B @ W2 -> A)
  k_gemm2<<<GB, 256, 0, stream>>>(B, Wt2, A, N);
  // P6: gather + LN + ReLU + residual -> O (fp32)
  k_gather_ln<<<(N + 15) / 16, 256, 0, stream>>>((const uint4*)A, meta, csr,
                                                 b2, g2, bl2, x,
                                                 O, nullptr, N);
}